// Round 4
// baseline (192.426 us; speedup 1.0000x reference)
//
#include <hip/hip_runtime.h>

#define M_DIM 8192
#define N_DIM 2048
#define K_DIM 2048

#define BM 256
#define BN 256
#define BK 64
#define NT (K_DIM / BK)

#define AS1 __attribute__((address_space(1)))
#define AS3 __attribute__((address_space(3)))

typedef float f32x4 __attribute__((ext_vector_type(4)));
typedef short s16x8 __attribute__((ext_vector_type(8)));

__device__ __forceinline__ unsigned short f2bf(float f) {
  unsigned int u = __float_as_uint(f);
  u += 0x7FFFu + ((u >> 16) & 1u);   // round-to-nearest-even
  return (unsigned short)(u >> 16);
}

// ---------------------------------------------------------------------------
// Kernel 1 (merged): blocks [0, M_DIM) do per-token int8 fake-quant of x;
// blocks [M_DIM, ...) do grouped int4 dequant of W.
// ---------------------------------------------------------------------------
__global__ __launch_bounds__(256) void prep_kernel(
    const float* __restrict__ x, const int* __restrict__ w,
    const float* __restrict__ ws, const float* __restrict__ wz,
    unsigned short* __restrict__ A, unsigned short* __restrict__ W) {
  const int tid = threadIdx.x;
  if (blockIdx.x < M_DIM) {
    const int t = blockIdx.x;
    const float4* r4 = (const float4*)(x + (size_t)t * K_DIM);
    float4 v0 = r4[tid];
    float4 v1 = r4[tid + 256];

    float mn = fminf(fminf(fminf(v0.x, v0.y), fminf(v0.z, v0.w)),
                     fminf(fminf(v1.x, v1.y), fminf(v1.z, v1.w)));
    float mx = fmaxf(fmaxf(fmaxf(v0.x, v0.y), fmaxf(v0.z, v0.w)),
                     fmaxf(fmaxf(v1.x, v1.y), fmaxf(v1.z, v1.w)));
#pragma unroll
    for (int off = 32; off > 0; off >>= 1) {
      mn = fminf(mn, __shfl_xor(mn, off));
      mx = fmaxf(mx, __shfl_xor(mx, off));
    }
    __shared__ float smn[4], smx[4];
    if ((tid & 63) == 0) { smn[tid >> 6] = mn; smx[tid >> 6] = mx; }
    __syncthreads();
    mn = fminf(fminf(smn[0], smn[1]), fminf(smn[2], smn[3]));
    mx = fmaxf(fmaxf(smx[0], smx[1]), fmaxf(smx[2], smx[3]));
    mn = fminf(mn, 0.0f);
    mx = fmaxf(mx, 0.0f);

    float scale = (mx - mn) / 255.0f;                 // (QMAX-QMIN)=255
    scale = fmaxf(scale, 1.1920928955078125e-07f);    // f32 eps = 2^-23
    const float inv = 1.0f / scale;                   // one IEEE div per token
    float zp = -128.0f - rintf(mn * inv);
    zp = fminf(fmaxf(zp, -128.0f), 127.0f);

    ushort4* Ao = (ushort4*)(A + (size_t)t * K_DIM);
    {
      float q; ushort4 r;
      q = rintf(v0.x * inv) + zp; q = fminf(fmaxf(q, -128.f), 127.f); r.x = f2bf((q - zp) * scale);
      q = rintf(v0.y * inv) + zp; q = fminf(fmaxf(q, -128.f), 127.f); r.y = f2bf((q - zp) * scale);
      q = rintf(v0.z * inv) + zp; q = fminf(fmaxf(q, -128.f), 127.f); r.z = f2bf((q - zp) * scale);
      q = rintf(v0.w * inv) + zp; q = fminf(fmaxf(q, -128.f), 127.f); r.w = f2bf((q - zp) * scale);
      Ao[tid] = r;
    }
    {
      float q; ushort4 r;
      q = rintf(v1.x * inv) + zp; q = fminf(fmaxf(q, -128.f), 127.f); r.x = f2bf((q - zp) * scale);
      q = rintf(v1.y * inv) + zp; q = fminf(fmaxf(q, -128.f), 127.f); r.y = f2bf((q - zp) * scale);
      q = rintf(v1.z * inv) + zp; q = fminf(fmaxf(q, -128.f), 127.f); r.z = f2bf((q - zp) * scale);
      q = rintf(v1.w * inv) + zp; q = fminf(fmaxf(q, -128.f), 127.f); r.w = f2bf((q - zp) * scale);
      Ao[tid + 256] = r;
    }
  } else {
    const int idx = (blockIdx.x - M_DIM) * 256 + tid;  // one 8-elem chunk
    const int o  = idx >> 8;                           // 2048/8 = 256 chunks/row
    const int ii = (idx & 255) * 8;
    const int g  = ii >> 5;                            // GROUPSIZE=32
    const float s = ws[o * 64 + g];
    const float z = wz[o * 64 + g];
    const int4* wp = (const int4*)(w + (size_t)o * K_DIM + ii);
    int4 a = wp[0], b = wp[1];
    ushort4 r0, r1;
    r0.x = f2bf(((float)a.x - z) * s);
    r0.y = f2bf(((float)a.y - z) * s);
    r0.z = f2bf(((float)a.z - z) * s);
    r0.w = f2bf(((float)a.w - z) * s);
    r1.x = f2bf(((float)b.x - z) * s);
    r1.y = f2bf(((float)b.y - z) * s);
    r1.z = f2bf(((float)b.z - z) * s);
    r1.w = f2bf(((float)b.w - z) * s);
    ushort4* Wo = (ushort4*)(W + (size_t)o * K_DIM + ii);
    Wo[0] = r0;
    Wo[1] = r1;
  }
}

// ---------------------------------------------------------------------------
// Kernel 2: C[M][N] = A[M][K] * B[N][K]^T, bf16 in, f32 out.
// 256x256x64, 8 waves (2M x 4N). Fused 2-barrier/tile schedule with
// register-neutral fragment read-ahead (quadrant order (0,0)(0,1)(1,1)(1,0)):
//   sec1: read bf-n1[4]+af-m1[8] (dead regs); stage 3 halves(kt+1)->oth;
//         48 MFMA: (0,0) gated on last-iter sec3 reads (1-cluster lead),
//         (0,1) after 16 MFMA, (1,1) after 32 MFMA (lgkm gates compiler-
//         counted; every gate covered by MFMA issue).
//   BAR_A: every wave's (1,1) gate was lgkmcnt(0) => all cur-buffer reads
//         chip-wide complete => cur writable.
//   sec2: stage A-h0(kt+2)->cur; vmcnt(2) (ledger 2 carried+6+2=10 ->
//         confirms exactly tile kt+1's 8 loads); BAR_B (oth now readable
//         by ALL waves -- vmcnt is per-wave, barrier makes it chip-wide).
//   sec3: read next tile's af-m0 + bf-n0 (into the bf-n1 array: parity
//         swap, zero extra regs); MFMA(1,0) covers their service.
// vmcnt never drains to 0 except the last two tiles. Per-quadrant kk order
// unchanged -> bit-identical accumulation vs previous passing kernels.
// ---------------------------------------------------------------------------

#define SFENCE() __builtin_amdgcn_sched_barrier(0)

#define RD_A(dst, MH, PLIT)                                                  \
  do {                                                                       \
    _Pragma("unroll") for (int i = 0; i < 4; ++i) {                          \
      _Pragma("unroll") for (int kk = 0; kk < 2; ++kk) {                     \
        dst[i][kk] = *(const s16x8*)((const char*)As + aoffB[kk] +           \
                      ((PLIT) * 32768 + ((MH) * 4 + i) * 2048));             \
      }                                                                      \
    }                                                                        \
  } while (0)

#define RD_B(dst, NH, PLIT)                                                  \
  do {                                                                       \
    _Pragma("unroll") for (int j = 0; j < 2; ++j) {                          \
      _Pragma("unroll") for (int kk = 0; kk < 2; ++kk) {                     \
        dst[j][kk] = *(const s16x8*)((const char*)Bs + boffB[kk] +           \
                      ((PLIT) * 32768 + ((NH) * 2 + j) * 2048));             \
      }                                                                      \
    }                                                                        \
  } while (0)

#define MFMA_Q(afX, bfX, MH, NH)                                             \
  do {                                                                       \
    _Pragma("unroll") for (int kk = 0; kk < 2; ++kk) {                       \
      _Pragma("unroll") for (int i = 0; i < 4; ++i) {                        \
        _Pragma("unroll") for (int j = 0; j < 2; ++j) {                      \
          acc[(MH) * 4 + i][(NH) * 2 + j] =                                  \
              __builtin_amdgcn_mfma_f32_16x16x32_bf16(                       \
                  afX[i][kk], bfX[j][kk],                                    \
                  acc[(MH) * 4 + i][(NH) * 2 + j], 0, 0, 0);                 \
        }                                                                    \
      }                                                                      \
    }                                                                        \
  } while (0)

// One half-tile = 128 rows x 64 cols bf16 = 2 glds rounds of (512 thr x 16B).
#define STAGE_A_HALF(KN, DSTP, H)                                            \
  do {                                                                       \
    _Pragma("unroll") for (int j = 0; j < 2; ++j) {                          \
      __builtin_amdgcn_global_load_lds(                                      \
          (const AS1 void*)(ag + (size_t)((H) * 2 + j) * 64 * K_DIM + (KN)), \
          (AS3 void*)(&As[(DSTP) * (BM * BK) + ((H) * 2 + j) * 4096 + tid * 8]), \
          16, 0, 0);                                                         \
    }                                                                        \
  } while (0)

#define STAGE_B_HALF(KN, DSTP, H)                                            \
  do {                                                                       \
    _Pragma("unroll") for (int j = 0; j < 2; ++j) {                          \
      __builtin_amdgcn_global_load_lds(                                      \
          (const AS1 void*)(bg + (size_t)((H) * 2 + j) * 64 * K_DIM + (KN)), \
          (AS3 void*)(&Bs[(DSTP) * (BN * BK) + ((H) * 2 + j) * 4096 + tid * 8]), \
          16, 0, 0);                                                         \
    }                                                                        \
  } while (0)

// One full K-tile iteration. PLIT is a compile-time literal (0/1); BN0/BN1
// are the two B-fragment register arrays (parity-swapped by the caller).
#define ITER(KT, PLIT, BN0, BN1)                                             \
  {                                                                          \
    const int k1 = ((KT) + 1) * BK;                                          \
    const int k2 = ((KT) + 2) * BK;                                          \
    /* ---- sec1 ---- */                                                     \
    RD_B(BN1, 1, PLIT);                                                      \
    RD_A(af1, 1, PLIT);                                                      \
    if ((KT) + 1 < NT) {                                                     \
      STAGE_A_HALF(k1, (PLIT) ^ 1, 1);                                       \
      STAGE_B_HALF(k1, (PLIT) ^ 1, 0);                                       \
      STAGE_B_HALF(k1, (PLIT) ^ 1, 1);                                       \
    }                                                                        \
    SFENCE();  /* pin read+stage issue before the MFMA cluster */            \
    __builtin_amdgcn_s_setprio(1);                                           \
    MFMA_Q(af0, BN0, 0, 0);                                                  \
    MFMA_Q(af0, BN1, 0, 1);                                                  \
    MFMA_Q(af1, BN1, 1, 1);                                                  \
    __builtin_amdgcn_s_setprio(0);                                           \
    SFENCE();                                                                \
    __builtin_amdgcn_s_barrier();  /* BAR_A: cur dead chip-wide */           \
    SFENCE();                                                                \
    /* ---- sec2 ---- */                                                     \
    if ((KT) + 2 < NT) STAGE_A_HALF(k2, PLIT, 0);                            \
    SFENCE();                                                                \
    if ((KT) + 2 < NT) {                                                     \
      asm volatile("s_waitcnt vmcnt(2)" ::: "memory");                       \
    } else {                                                                 \
      asm volatile("s_waitcnt vmcnt(0)" ::: "memory");                       \
    }                                                                        \
    SFENCE();                                                                \
    __builtin_amdgcn_s_barrier();  /* BAR_B: oth valid chip-wide */          \
    SFENCE();                                                                \
    /* ---- sec3 ---- */                                                     \
    if ((KT) + 1 < NT) {                                                     \
      RD_A(af0, 0, (PLIT) ^ 1);                                              \
      RD_B(BN1, 0, (PLIT) ^ 1);  /* next tile's n0 -> old n1 array */        \
    }                                                                        \
    SFENCE();  /* pin read issue before MFMA(1,0) so service overlaps */     \
    __builtin_amdgcn_s_setprio(1);                                           \
    MFMA_Q(af1, BN0, 1, 0);                                                  \
    __builtin_amdgcn_s_setprio(0);                                           \
  }

__global__ __launch_bounds__(512, 2) void gemm_kernel(
    const unsigned short* __restrict__ A,
    const unsigned short* __restrict__ B,
    float* __restrict__ C) {
  __shared__ unsigned short As[2 * BM * BK];  // 64 KB, double-buffered
  __shared__ unsigned short Bs[2 * BN * BK];  // 64 KB, double-buffered

  const int tid = threadIdx.x;
  // XCD swizzle: linear dispatch id = by*8+bx, id%8 ~ XCD. Each XCD gets a
  // contiguous 4-slab M range x full N (bijective, nwg=256 = 8*32).
  const int id  = blockIdx.y * 8 + blockIdx.x;
  const int nid = (id & 7) * 32 + (id >> 3);
  const int bm  = (nid >> 3) * BM;
  const int bn  = (nid & 7) * BN;

  const int lane  = tid & 63;
  const int wv    = tid >> 6;
  const int waveM = (wv >> 2) * 128;   // 2 M-waves
  const int waveN = (wv & 3) * 64;     // 4 N-waves
  const int quad  = lane >> 4;
  const int l16   = lane & 15;

  // --- staging: row = trow + round*64, global chunk (phys) = (tid&7)^(trow&7),
  // LDS dest linear at tid*16B.
  const int trow = tid >> 3;                    // 0..63
  const int phys = (tid & 7) ^ (trow & 7);
  const unsigned short* ag = A + (size_t)(bm + trow) * K_DIM + phys * 8;
  const unsigned short* bg = B + (size_t)(bn + trow) * K_DIM + phys * 8;

  // --- fragment base byte-offsets (per kk slice; undo swizzle).
  // slot(kk) = quad ^ (l16&7) ^ (kk*4)  (since chunk = quad + kk*4 and
  // quad<4 => '+' == '^'). All mi/ni/buffer terms are compile-time adds.
  int aoffB[2], boffB[2];
#pragma unroll
  for (int kk = 0; kk < 2; ++kk) {
    aoffB[kk] = ((waveM + l16) * BK + ((quad ^ (l16 & 7) ^ (kk * 4)) * 8)) * 2;
    boffB[kk] = ((waveN + l16) * BK + ((quad ^ (l16 & 7) ^ (kk * 4)) * 8)) * 2;
  }

  f32x4 acc[8][4] = {};
  s16x8 af0[4][2], af1[4][2];   // A m-half fragments
  s16x8 bX[2][2], bY[2][2];     // B n-half fragments (parity-swapped roles)

  // --- prologue: tile 0 complete (buf 0) + A-h0(1) (buf 1, stays in flight);
  // vmcnt(2) confirms exactly tile 0's 8 loads.
  STAGE_A_HALF(0, 0, 0);
  STAGE_A_HALF(0, 0, 1);
  STAGE_B_HALF(0, 0, 0);
  STAGE_B_HALF(0, 0, 1);
  STAGE_A_HALF(BK, 1, 0);
  SFENCE();
  asm volatile("s_waitcnt vmcnt(2)" ::: "memory");
  SFENCE();
  __builtin_amdgcn_s_barrier();
  SFENCE();
  RD_A(af0, 0, 0);
  RD_B(bX, 0, 0);

  for (int kt = 0; kt < NT; kt += 2) {
    ITER(kt, 0, bX, bY);
    ITER(kt + 1, 1, bY, bX);
  }

  // --- epilogue: C/D layout col=lane&15, row=quad*4+reg (unchanged order)
#pragma unroll
  for (int mi = 0; mi < 8; ++mi) {
#pragma unroll
    for (int ni = 0; ni < 4; ++ni) {
      const int o = bn + waveN + ni * 16 + l16;
#pragma unroll
      for (int r = 0; r < 4; ++r) {
        const int row = bm + waveM + mi * 16 + quad * 4 + r;
        C[(size_t)row * N_DIM + o] = acc[mi][ni][r];
      }
    }
  }
}

// ---------------------------------------------------------------------------
extern "C" void kernel_launch(void* const* d_in, const int* in_sizes, int n_in,
                              void* d_out, int out_size, void* d_ws, size_t ws_size,
                              hipStream_t stream) {
  const float* x        = (const float*)d_in[0];
  const int*   w_int    = (const int*)d_in[1];
  const float* w_scales = (const float*)d_in[2];
  const float* w_zeros  = (const float*)d_in[3];
  float* out = (float*)d_out;

  unsigned short* Aq = (unsigned short*)d_ws;                 // 8192*2048 bf16
  unsigned short* Wq = Aq + (size_t)M_DIM * K_DIM;            // 2048*2048 bf16

  const int prep_blocks = M_DIM + (N_DIM * (K_DIM / 8)) / 256;  // 8192 + 2048
  prep_kernel<<<prep_blocks, 256, 0, stream>>>(x, w_int, w_scales, w_zeros, Aq, Wq);
  dim3 grid(N_DIM / BN, M_DIM / BM);   // (8, 32) = 256 blocks = 1/CU
  gemm_kernel<<<grid, 512, 0, stream>>>(Aq, Wq, out);
}

// Round 5
// 182.317 us; speedup vs baseline: 1.0554x; 1.0554x over previous
//
#include <hip/hip_runtime.h>

#define M_DIM 8192
#define N_DIM 2048
#define K_DIM 2048

#define BM 256
#define BN 256
#define BK 64
#define NT (K_DIM / BK)

#define AS1 __attribute__((address_space(1)))
#define AS3 __attribute__((address_space(3)))

typedef float f32x4 __attribute__((ext_vector_type(4)));
typedef short s16x8 __attribute__((ext_vector_type(8)));

__device__ __forceinline__ unsigned short f2bf(float f) {
  unsigned int u = __float_as_uint(f);
  u += 0x7FFFu + ((u >> 16) & 1u);   // round-to-nearest-even
  return (unsigned short)(u >> 16);
}

// ---------------------------------------------------------------------------
// Kernel 1 (merged): blocks [0, M_DIM) do per-token int8 fake-quant of x;
// blocks [M_DIM, ...) do grouped int4 dequant of W.
// ---------------------------------------------------------------------------
__global__ __launch_bounds__(256) void prep_kernel(
    const float* __restrict__ x, const int* __restrict__ w,
    const float* __restrict__ ws, const float* __restrict__ wz,
    unsigned short* __restrict__ A, unsigned short* __restrict__ W) {
  const int tid = threadIdx.x;
  if (blockIdx.x < M_DIM) {
    const int t = blockIdx.x;
    const float4* r4 = (const float4*)(x + (size_t)t * K_DIM);
    float4 v0 = r4[tid];
    float4 v1 = r4[tid + 256];

    float mn = fminf(fminf(fminf(v0.x, v0.y), fminf(v0.z, v0.w)),
                     fminf(fminf(v1.x, v1.y), fminf(v1.z, v1.w)));
    float mx = fmaxf(fmaxf(fmaxf(v0.x, v0.y), fmaxf(v0.z, v0.w)),
                     fmaxf(fmaxf(v1.x, v1.y), fmaxf(v1.z, v1.w)));
#pragma unroll
    for (int off = 32; off > 0; off >>= 1) {
      mn = fminf(mn, __shfl_xor(mn, off));
      mx = fmaxf(mx, __shfl_xor(mx, off));
    }
    __shared__ float smn[4], smx[4];
    if ((tid & 63) == 0) { smn[tid >> 6] = mn; smx[tid >> 6] = mx; }
    __syncthreads();
    mn = fminf(fminf(smn[0], smn[1]), fminf(smn[2], smn[3]));
    mx = fmaxf(fmaxf(smx[0], smx[1]), fmaxf(smx[2], smx[3]));
    mn = fminf(mn, 0.0f);
    mx = fmaxf(mx, 0.0f);

    float scale = (mx - mn) / 255.0f;                 // (QMAX-QMIN)=255
    scale = fmaxf(scale, 1.1920928955078125e-07f);    // f32 eps = 2^-23
    const float inv = 1.0f / scale;                   // one IEEE div per token
    float zp = -128.0f - rintf(mn * inv);
    zp = fminf(fmaxf(zp, -128.0f), 127.0f);

    ushort4* Ao = (ushort4*)(A + (size_t)t * K_DIM);
    {
      float q; ushort4 r;
      q = rintf(v0.x * inv) + zp; q = fminf(fmaxf(q, -128.f), 127.f); r.x = f2bf((q - zp) * scale);
      q = rintf(v0.y * inv) + zp; q = fminf(fmaxf(q, -128.f), 127.f); r.y = f2bf((q - zp) * scale);
      q = rintf(v0.z * inv) + zp; q = fminf(fmaxf(q, -128.f), 127.f); r.z = f2bf((q - zp) * scale);
      q = rintf(v0.w * inv) + zp; q = fminf(fmaxf(q, -128.f), 127.f); r.w = f2bf((q - zp) * scale);
      Ao[tid] = r;
    }
    {
      float q; ushort4 r;
      q = rintf(v1.x * inv) + zp; q = fminf(fmaxf(q, -128.f), 127.f); r.x = f2bf((q - zp) * scale);
      q = rintf(v1.y * inv) + zp; q = fminf(fmaxf(q, -128.f), 127.f); r.y = f2bf((q - zp) * scale);
      q = rintf(v1.z * inv) + zp; q = fminf(fmaxf(q, -128.f), 127.f); r.z = f2bf((q - zp) * scale);
      q = rintf(v1.w * inv) + zp; q = fminf(fmaxf(q, -128.f), 127.f); r.w = f2bf((q - zp) * scale);
      Ao[tid + 256] = r;
    }
  } else {
    const int idx = (blockIdx.x - M_DIM) * 256 + tid;  // one 8-elem chunk
    const int o  = idx >> 8;                           // 2048/8 = 256 chunks/row
    const int ii = (idx & 255) * 8;
    const int g  = ii >> 5;                            // GROUPSIZE=32
    const float s = ws[o * 64 + g];
    const float z = wz[o * 64 + g];
    const int4* wp = (const int4*)(w + (size_t)o * K_DIM + ii);
    int4 a = wp[0], b = wp[1];
    ushort4 r0, r1;
    r0.x = f2bf(((float)a.x - z) * s);
    r0.y = f2bf(((float)a.y - z) * s);
    r0.z = f2bf(((float)a.z - z) * s);
    r0.w = f2bf(((float)a.w - z) * s);
    r1.x = f2bf(((float)b.x - z) * s);
    r1.y = f2bf(((float)b.y - z) * s);
    r1.z = f2bf(((float)b.z - z) * s);
    r1.w = f2bf(((float)b.w - z) * s);
    ushort4* Wo = (ushort4*)(W + (size_t)o * K_DIM + ii);
    Wo[0] = r0;
    Wo[1] = r1;
  }
}

// ---------------------------------------------------------------------------
// Kernel 2: C[M][N] = A[M][K] * B[N][K]^T, bf16 in, f32 out.
// Round-4 skeleton (2 barriers/tile, counted vmcnt, verified ledgers) with
// HAND-GATED fragment reads: all ds_read_b128 are inline asm (invisible to
// the compiler's waitcnt insertion), and the ONLY lgkm waits in the loop
// are our counted gates. Per-wave in-order DS ledger:
//   enter sec1: 12 outstanding (prev sec3: af0 x8, bn0 x4)
//   sec1 issues bn1 x4, af1 x8 -> 24
//   G(0,0)=lgkmcnt(12): retires af0+bn0; the 12 new reads service UNDER
//     the 16 MFMAs of (0,0)          G(0,1)=lgkmcnt(8): retires bn1
//   G(1,1)=lgkmcnt(0): retires af1 (48 MFMAs of cover) and re-establishes
//     BAR_A's proof that the current buffer is fully read chip-wide.
//   sec3 issues next tile's af0' x8, bn0' x4 under MFMA(1,0) -> 12. loop.
// vm ledger unchanged from round 3/4: sec2's vmcnt(2) confirms exactly the
// 8 loads of tile kt+1; never drains to 0 except the last two tiles.
// Rule #18: every asm waitcnt is followed by sched_barrier(0) so MFMAs
// cannot be hoisted above it. MFMA order/operands identical to the passing
// kernels -> bit-identical numerics.
// ---------------------------------------------------------------------------

#define SFENCE() __builtin_amdgcn_sched_barrier(0)

#define DSR(dst, addr, IMM)                                                  \
  asm volatile("ds_read_b128 %0, %1 offset:%2"                               \
               : "=v"(dst) : "v"(addr), "i"(IMM))

#define LGKM_GATE(N)                                                         \
  do {                                                                       \
    asm volatile("s_waitcnt lgkmcnt(%0)" :: "i"(N) : "memory");              \
    SFENCE();                                                                \
  } while (0)

#define RD_A(dst, MH, PLIT)                                                  \
  do {                                                                       \
    _Pragma("unroll") for (int i = 0; i < 4; ++i) {                          \
      _Pragma("unroll") for (int kk = 0; kk < 2; ++kk) {                     \
        DSR(dst[i][kk], a_addr[kk],                                          \
            (PLIT) * 32768 + ((MH) * 4 + i) * 2048);                         \
      }                                                                      \
    }                                                                        \
  } while (0)

#define RD_B(dst, NH, PLIT)                                                  \
  do {                                                                       \
    _Pragma("unroll") for (int j = 0; j < 2; ++j) {                          \
      _Pragma("unroll") for (int kk = 0; kk < 2; ++kk) {                     \
        DSR(dst[j][kk], b_addr[kk],                                          \
            (PLIT) * 32768 + ((NH) * 2 + j) * 2048);                         \
      }                                                                      \
    }                                                                        \
  } while (0)

#define MFMA_Q(afX, bfX, MH, NH)                                             \
  do {                                                                       \
    __builtin_amdgcn_s_setprio(1);                                           \
    _Pragma("unroll") for (int kk = 0; kk < 2; ++kk) {                       \
      _Pragma("unroll") for (int i = 0; i < 4; ++i) {                        \
        _Pragma("unroll") for (int j = 0; j < 2; ++j) {                      \
          acc[(MH) * 4 + i][(NH) * 2 + j] =                                  \
              __builtin_amdgcn_mfma_f32_16x16x32_bf16(                       \
                  afX[i][kk], bfX[j][kk],                                    \
                  acc[(MH) * 4 + i][(NH) * 2 + j], 0, 0, 0);                 \
        }                                                                    \
      }                                                                      \
    }                                                                        \
    __builtin_amdgcn_s_setprio(0);                                           \
  } while (0)

// One half-tile = 128 rows x 64 cols bf16 = 2 glds rounds of (512 thr x 16B).
#define STAGE_A_HALF(KN, DSTP, H)                                            \
  do {                                                                       \
    _Pragma("unroll") for (int j = 0; j < 2; ++j) {                          \
      __builtin_amdgcn_global_load_lds(                                      \
          (const AS1 void*)(ag + (size_t)((H) * 2 + j) * 64 * K_DIM + (KN)), \
          (AS3 void*)(&As[(DSTP) * (BM * BK) + ((H) * 2 + j) * 4096 + tid * 8]), \
          16, 0, 0);                                                         \
    }                                                                        \
  } while (0)

#define STAGE_B_HALF(KN, DSTP, H)                                            \
  do {                                                                       \
    _Pragma("unroll") for (int j = 0; j < 2; ++j) {                          \
      __builtin_amdgcn_global_load_lds(                                      \
          (const AS1 void*)(bg + (size_t)((H) * 2 + j) * 64 * K_DIM + (KN)), \
          (AS3 void*)(&Bs[(DSTP) * (BN * BK) + ((H) * 2 + j) * 4096 + tid * 8]), \
          16, 0, 0);                                                         \
    }                                                                        \
  } while (0)

// One full K-tile iteration. PLIT is a compile-time literal (0/1); BN0/BN1
// are the two B-fragment register arrays (parity-swapped by the caller).
#define ITER(KT, PLIT, BN0, BN1)                                             \
  {                                                                          \
    const int k1 = ((KT) + 1) * BK;                                          \
    const int k2 = ((KT) + 2) * BK;                                          \
    /* ---- sec1: issue reads (bn1 first, then af1) + 3-half stage ---- */   \
    RD_B(BN1, 1, PLIT);                                                      \
    RD_A(af1, 1, PLIT);                                                      \
    if ((KT) + 1 < NT) {                                                     \
      STAGE_A_HALF(k1, (PLIT) ^ 1, 1);                                       \
      STAGE_B_HALF(k1, (PLIT) ^ 1, 0);                                       \
      STAGE_B_HALF(k1, (PLIT) ^ 1, 1);                                       \
    }                                                                        \
    SFENCE();                                                                \
    LGKM_GATE(12);             /* af0+bn0 ready; 12 new reads in flight */   \
    MFMA_Q(af0, BN0, 0, 0);                                                  \
    SFENCE();                                                                \
    LGKM_GATE(8);              /* bn1 ready */                               \
    MFMA_Q(af0, BN1, 0, 1);                                                  \
    SFENCE();                                                                \
    LGKM_GATE(0);              /* af1 ready; cur buffer fully read */        \
    MFMA_Q(af1, BN1, 1, 1);                                                  \
    SFENCE();                                                                \
    __builtin_amdgcn_s_barrier();  /* BAR_A: cur dead chip-wide */           \
    SFENCE();                                                                \
    /* ---- sec2 ---- */                                                     \
    if ((KT) + 2 < NT) STAGE_A_HALF(k2, PLIT, 0);                            \
    SFENCE();                                                                \
    if ((KT) + 2 < NT) {                                                     \
      asm volatile("s_waitcnt vmcnt(2)" ::: "memory");                       \
    } else {                                                                 \
      asm volatile("s_waitcnt vmcnt(0)" ::: "memory");                       \
    }                                                                        \
    SFENCE();                                                                \
    __builtin_amdgcn_s_barrier();  /* BAR_B: oth valid chip-wide */          \
    SFENCE();                                                                \
    /* ---- sec3: next tile's reads (af0' then bn0') under MFMA(1,0) */      \
    if ((KT) + 1 < NT) {                                                     \
      RD_A(af0, 0, (PLIT) ^ 1);                                              \
      RD_B(BN1, 0, (PLIT) ^ 1);  /* next tile's n0 -> old n1 array */        \
    }                                                                        \
    SFENCE();                                                                \
    MFMA_Q(af1, BN0, 1, 0);    /* af1, bn0 already gated/retired */          \
  }

__global__ __launch_bounds__(512, 2) void gemm_kernel(
    const unsigned short* __restrict__ A,
    const unsigned short* __restrict__ B,
    float* __restrict__ C) {
  __shared__ unsigned short As[2 * BM * BK];  // 64 KB, double-buffered
  __shared__ unsigned short Bs[2 * BN * BK];  // 64 KB, double-buffered

  const int tid = threadIdx.x;
  // XCD swizzle: linear dispatch id = by*8+bx, id%8 ~ XCD. Each XCD gets a
  // contiguous 4-slab M range x full N (bijective, nwg=256 = 8*32).
  const int id  = blockIdx.y * 8 + blockIdx.x;
  const int nid = (id & 7) * 32 + (id >> 3);
  const int bm  = (nid >> 3) * BM;
  const int bn  = (nid & 7) * BN;

  const int lane  = tid & 63;
  const int wv    = tid >> 6;
  const int waveM = (wv >> 2) * 128;   // 2 M-waves
  const int waveN = (wv & 3) * 64;     // 4 N-waves
  const int quad  = lane >> 4;
  const int l16   = lane & 15;

  // --- staging: row = trow + round*64, global chunk (phys) = (tid&7)^(trow&7),
  // LDS dest linear at tid*16B.
  const int trow = tid >> 3;                    // 0..63
  const int phys = (tid & 7) ^ (trow & 7);
  const unsigned short* ag = A + (size_t)(bm + trow) * K_DIM + phys * 8;
  const unsigned short* bg = B + (size_t)(bn + trow) * K_DIM + phys * 8;

  // --- fragment base LDS byte addresses (per kk slice; undo swizzle).
  // slot(kk) = quad ^ (l16&7) ^ (kk*4); mi/ni/buffer terms are asm
  // compile-time immediates (offset: PLIT*32768 + frag*2048).
  const unsigned asb = (unsigned)(size_t)(AS3 void*)&As[0];
  const unsigned bsb = (unsigned)(size_t)(AS3 void*)&Bs[0];
  unsigned a_addr[2], b_addr[2];
#pragma unroll
  for (int kk = 0; kk < 2; ++kk) {
    const unsigned sw = (unsigned)((quad ^ (l16 & 7) ^ (kk * 4)) * 16);
    a_addr[kk] = asb + (unsigned)((waveM + l16) * BK * 2) + sw;
    b_addr[kk] = bsb + (unsigned)((waveN + l16) * BK * 2) + sw;
  }

  f32x4 acc[8][4] = {};
  s16x8 af0[4][2], af1[4][2];   // A m-half fragments
  s16x8 bX[2][2], bY[2][2];     // B n-half fragments (parity-swapped roles)

  // --- prologue: tile 0 complete (buf 0) + A-h0(1) (buf 1, stays in flight);
  // vmcnt(2) confirms exactly tile 0's 8 loads.
  STAGE_A_HALF(0, 0, 0);
  STAGE_A_HALF(0, 0, 1);
  STAGE_B_HALF(0, 0, 0);
  STAGE_B_HALF(0, 0, 1);
  STAGE_A_HALF(BK, 1, 0);
  SFENCE();
  asm volatile("s_waitcnt vmcnt(2)" ::: "memory");
  SFENCE();
  __builtin_amdgcn_s_barrier();
  SFENCE();
  RD_A(af0, 0, 0);   // 8 reads   (positions 1-8 in the lgkm ledger)
  RD_B(bX, 0, 0);    // 4 reads   (positions 9-12)
  SFENCE();

  for (int kt = 0; kt < NT; kt += 2) {
    ITER(kt, 0, bX, bY);
    ITER(kt + 1, 1, bY, bX);
  }

  // --- epilogue: C/D layout col=lane&15, row=quad*4+reg (unchanged order)
#pragma unroll
  for (int mi = 0; mi < 8; ++mi) {
#pragma unroll
    for (int ni = 0; ni < 4; ++ni) {
      const int o = bn + waveN + ni * 16 + l16;
#pragma unroll
      for (int r = 0; r < 4; ++r) {
        const int row = bm + waveM + mi * 16 + quad * 4 + r;
        C[(size_t)row * N_DIM + o] = acc[mi][ni][r];
      }
    }
  }
}

// ---------------------------------------------------------------------------
extern "C" void kernel_launch(void* const* d_in, const int* in_sizes, int n_in,
                              void* d_out, int out_size, void* d_ws, size_t ws_size,
                              hipStream_t stream) {
  const float* x        = (const float*)d_in[0];
  const int*   w_int    = (const int*)d_in[1];
  const float* w_scales = (const float*)d_in[2];
  const float* w_zeros  = (const float*)d_in[3];
  float* out = (float*)d_out;

  unsigned short* Aq = (unsigned short*)d_ws;                 // 8192*2048 bf16
  unsigned short* Wq = Aq + (size_t)M_DIM * K_DIM;            // 2048*2048 bf16

  const int prep_blocks = M_DIM + (N_DIM * (K_DIM / 8)) / 256;  // 8192 + 2048
  prep_kernel<<<prep_blocks, 256, 0, stream>>>(x, w_int, w_scales, w_zeros, Aq, Wq);
  dim3 grid(N_DIM / BN, M_DIM / BM);   // (8, 32) = 256 blocks = 1/CU
  gemm_kernel<<<grid, 512, 0, stream>>>(Aq, Wq, out);
}